// Round 19
// baseline (419.857 us; speedup 1.0000x reference)
//
#include <hip/hip_runtime.h>

typedef unsigned short u16;
typedef unsigned int u32;

using f32x4 = __attribute__((ext_vector_type(4))) float;
using bf16x8 = __attribute__((ext_vector_type(8))) __bf16;

// ---------- constants ----------
#define HN 2048
#define KVD 512
#define TOKENS 2048          // B*T
#define N1 3712              // GEMM1 N (3648 padded to 29*128)
#define K2W 576              // GEMM2 K
#define N2 7168              // GEMM2 N: w(2048) a(2048) g(2048) v(512) k(512)

// ---------- workspace layout (bytes) — lifetime-aliased, peak 230.7 MB ----------
#define OFF_Y1   0ull
#define OFF_OO   0ull
#define OFF_XG   16777216ull
#define OFF_Y2   30408704ull
#define OFF_OUTR 30408704ull
#define OFF_BT1  89128960ull
#define OFF_XB   104333312ull
#define OFF_W2T  89128960ull
#define OFF_X2   97386496ull
#define OFF_OT   89128960ull
#define OFF_RR   112721920ull
#define OFF_DEC  129499136ull
#define OFF_KR   146276352ull
#define OFF_VV   163053568ull
#define OFF_AA   179830784ull
#define OFF_BB   196608000ull
#define OFF_RKB  213385216ull            // f32 [64 chains][1024][2] = 512 KB
#define OFF_RD   213909504ull            // f32 [2048][2048] = 16.8 MB
#define WS_NEED  230686720ull

// ---------- helpers ----------
__device__ __forceinline__ u16 f2bf(float f) {
    u32 u = __float_as_uint(f);
    u32 r = u + 0x7fffu + ((u >> 16) & 1u);
    return (u16)(r >> 16);
}
__device__ __forceinline__ float sigm(float x) { return 1.f / (1.f + expf(-x)); }
__device__ __forceinline__ float wsum(float v) {
#pragma unroll
    for (int m = 32; m > 0; m >>= 1) v += __shfl_xor(v, m, 64);
    return v;
}
// sum across each 16-lane DPP row via row_ror 1,2,4,8; result in all lanes of the row
__device__ __forceinline__ float rowsum16(float v) {
    float t;
    t = __uint_as_float(__builtin_amdgcn_update_dpp(0, __float_as_uint(v), 0x121, 0xf, 0xf, true));
    v += t;
    t = __uint_as_float(__builtin_amdgcn_update_dpp(0, __float_as_uint(v), 0x122, 0xf, 0xf, true));
    v += t;
    t = __uint_as_float(__builtin_amdgcn_update_dpp(0, __float_as_uint(v), 0x124, 0xf, 0xf, true));
    v += t;
    t = __uint_as_float(__builtin_amdgcn_update_dpp(0, __float_as_uint(v), 0x128, 0xf, 0xf, true));
    v += t;
    return v;
}

typedef __attribute__((address_space(1))) const void glob_t;
typedef __attribute__((address_space(3))) void lds_t;
__device__ __forceinline__ void gload_lds16(const void* g, void* l) {
    __builtin_amdgcn_global_load_lds((glob_t*)g, (lds_t*)l, 16, 0, 0);
}

// ---------- weight prep: tiled transposes (coalesced read AND write) ----------
__global__ __launch_bounds__(256) void k_prep_bt1(const float* __restrict__ wavgk1,
                                                  const float* __restrict__ RKV,
                                                  u16* __restrict__ BT1) {
    __shared__ float tile[64][65];
    const int bn = blockIdx.x >> 5;        // 0..57
    const int bk = blockIdx.x & 31;        // 0..31
    const int n0 = bn << 6, k0 = bk << 6;
    const int c = threadIdx.x & 63, q = threadIdx.x >> 6;
#pragma unroll
    for (int i = 0; i < 16; ++i) {
        const int r = (q << 4) + i;
        float v = 0.f;
        if (bn < 9)       v = wavgk1[(size_t)(k0 + r) * 576 + n0 + c];
        else if (bn < 57) v = RKV[(size_t)(k0 + r) * 3072 + (n0 + c - 576)];
        tile[r][c] = v;
    }
    __syncthreads();
#pragma unroll
    for (int i = 0; i < 16; ++i) {
        const int rw = (q << 4) + i;
        BT1[(size_t)(n0 + rw) * 2048 + k0 + c] = f2bf(tile[c][rw]);
    }
}

__global__ __launch_bounds__(256) void k_prep_w2t(const float* __restrict__ w2, const float* __restrict__ a2,
                                                  const float* __restrict__ g2, const float* __restrict__ v2,
                                                  const float* __restrict__ k2, u16* __restrict__ W2T) {
    int idx = blockIdx.x * 256 + threadIdx.x;   // n*576 + c, n<7168
    int n = idx / 576, c = idx - n * 576;
    float v = 0.f;
    if (n < 2048)      { if (c < 96)              v = w2[(size_t)c * 2048 + n]; }
    else if (n < 4096) { if (c >= 96 && c < 192)  v = a2[(size_t)(c - 96) * 2048 + (n - 2048)]; }
    else if (n < 6144) { if (c >= 192 && c < 448) v = g2[(size_t)(c - 192) * 2048 + (n - 4096)]; }
    else if (n < 6656) { if (c >= 448 && c < 512) v = v2[(size_t)(c - 448) * 512 + (n - 6144)]; }
    else               { if (c >= 512)            v = k2[(size_t)(c - 512) * 512 + (n - 6656)]; }
    W2T[idx] = f2bf(v);
}

// OT[n][k] = O[k][n], 2048x2048, 64x64 tiles
__global__ __launch_bounds__(256) void k_prep_ot(const float* __restrict__ O, u16* __restrict__ OT) {
    __shared__ float tile[64][65];
    const int bn = blockIdx.x >> 5, bk = blockIdx.x & 31;
    const int n0 = bn << 6, k0 = bk << 6;
    const int c = threadIdx.x & 63, q = threadIdx.x >> 6;
#pragma unroll
    for (int i = 0; i < 16; ++i) {
        const int r = (q << 4) + i;
        tile[r][c] = O[(size_t)(k0 + r) * 2048 + n0 + c];
    }
    __syncthreads();
#pragma unroll
    for (int i = 0; i < 16; ++i) {
        const int rw = (q << 4) + i;
        OT[(size_t)(n0 + rw) * 2048 + k0 + c] = f2bf(tile[c][rw]);
    }
}

// ---------- rmsnorm(x_in, ln1) -> bf16 ----------
__global__ __launch_bounds__(256) void k_rms1(const float* __restrict__ X,
                                              const float* __restrict__ ln1,
                                              u16* __restrict__ XB) {
    const int t = blockIdx.x, tid = threadIdx.x;
    const float* row = X + ((size_t)t << 11);
    float4 v0 = *(const float4*)(row + tid * 8);
    float4 v1 = *(const float4*)(row + tid * 8 + 4);
    float ss = v0.x*v0.x + v0.y*v0.y + v0.z*v0.z + v0.w*v0.w
             + v1.x*v1.x + v1.y*v1.y + v1.z*v1.z + v1.w*v1.w;
    ss = wsum(ss);
    __shared__ float red[4];
    if ((tid & 63) == 0) red[tid >> 6] = ss;
    __syncthreads();
    float scale = rsqrtf((red[0] + red[1] + red[2] + red[3]) * (1.f / 2048.f) + 1e-6f);
    float4 w0_ = *(const float4*)(ln1 + tid * 8);
    float4 w1_ = *(const float4*)(ln1 + tid * 8 + 4);
    u16* o = XB + ((size_t)t << 11) + tid * 8;
    o[0] = f2bf(v0.x * scale * w0_.x); o[1] = f2bf(v0.y * scale * w0_.y);
    o[2] = f2bf(v0.z * scale * w0_.z); o[3] = f2bf(v0.w * scale * w0_.w);
    o[4] = f2bf(v1.x * scale * w1_.x); o[5] = f2bf(v1.y * scale * w1_.y);
    o[6] = f2bf(v1.z * scale * w1_.z); o[7] = f2bf(v1.w * scale * w1_.w);
}

// ---------- generic bf16 MFMA GEMM with LDS chunk swizzle ----------
__global__ __launch_bounds__(256) void k_gemm(const u16* __restrict__ A,
                                              const u16* __restrict__ Bt,
                                              float* __restrict__ C,
                                              int M, int N, int K) {
    __shared__ __align__(16) u16 tA[4096];  // [128 rows][32 k]
    __shared__ __align__(16) u16 tB[4096];
    const int tid = threadIdx.x;
    const int w = tid >> 6, l = tid & 63;
    const int bm = blockIdx.x << 7, bn = blockIdx.y << 7;
    const int wm = (w >> 1) << 6, wn = (w & 1) << 6;
    const int lrow = l >> 2;        // 0..15 (staged row within 16-row group)
    const int lk = (((l & 3) ^ ((l >> 3) & 3)) << 3);   // pre-swizzled global chunk
    f32x4 acc[4][4] = {};
    const size_t rA0 = (size_t)(bm + (w << 4) + lrow) * K;
    const size_t rA1 = (size_t)(bm + ((w + 4) << 4) + lrow) * K;
    const size_t rB0 = (size_t)(bn + (w << 4) + lrow) * K;
    const size_t rB1 = (size_t)(bn + ((w + 4) << 4) + lrow) * K;
    const int frow = l & 15;
    const int koff = (((l >> 4) ^ ((l >> 1) & 3)) << 3);  // swizzled read chunk
    for (int kt = 0; kt < K; kt += 32) {
        gload_lds16(A + rA0 + kt + lk, &tA[w << 9]);
        gload_lds16(A + rA1 + kt + lk, &tA[2048 + (w << 9)]);
        gload_lds16(Bt + rB0 + kt + lk, &tB[w << 9]);
        gload_lds16(Bt + rB1 + kt + lk, &tB[2048 + (w << 9)]);
        __syncthreads();
        bf16x8 av[4], bv[4];
#pragma unroll
        for (int i = 0; i < 4; ++i) {
            av[i] = *(const bf16x8*)&tA[((wm + (i << 4) + frow) << 5) + koff];
            bv[i] = *(const bf16x8*)&tB[((wn + (i << 4) + frow) << 5) + koff];
        }
#pragma unroll
        for (int i = 0; i < 4; ++i)
#pragma unroll
            for (int j = 0; j < 4; ++j)
                acc[i][j] = __builtin_amdgcn_mfma_f32_16x16x32_bf16(av[i], bv[j], acc[i][j], 0, 0, 0);
        __syncthreads();
    }
    const int crow = bm + wm + ((l >> 4) << 2);
    const int ccol = bn + wn + (l & 15);
#pragma unroll
    for (int i = 0; i < 4; ++i)
#pragma unroll
        for (int j = 0; j < 4; ++j)
#pragma unroll
            for (int jj = 0; jj < 4; ++jj)
                C[(size_t)(crow + (i << 4) + jj) * N + ccol + (j << 4)] = acc[i][j][jj];
}

// ---------- GEMM2 specialization: block-diagonal W2T, per-segment true K ----------
__global__ __launch_bounds__(256) void k_gemm2(const u16* __restrict__ A,
                                               const u16* __restrict__ Bt,
                                               float* __restrict__ C) {
    __shared__ __align__(16) u16 tA[4096];
    __shared__ __align__(16) u16 tB[4096];
    const int tid = threadIdx.x;
    const int w = tid >> 6, l = tid & 63;
    const int by = blockIdx.y;
    int c0, K;
    if (by < 16)      { c0 = 0;   K = 96; }
    else if (by < 32) { c0 = 96;  K = 96; }
    else if (by < 48) { c0 = 192; K = 256; }
    else if (by < 52) { c0 = 448; K = 64; }
    else              { c0 = 512; K = 64; }
    const int n0 = by << 7;
    const int bm = blockIdx.x << 7;
    const int wm = (w >> 1) << 6, wn = (w & 1) << 6;
    const int lrow = l >> 2;
    const int lk = (((l & 3) ^ ((l >> 3) & 3)) << 3);
    f32x4 acc[4][4] = {};
    const size_t rA0 = (size_t)(bm + (w << 4) + lrow) * 576 + c0;
    const size_t rA1 = (size_t)(bm + ((w + 4) << 4) + lrow) * 576 + c0;
    const size_t rB0 = (size_t)(n0 + (w << 4) + lrow) * 576 + c0;
    const size_t rB1 = (size_t)(n0 + ((w + 4) << 4) + lrow) * 576 + c0;
    const int frow = l & 15;
    const int koff = (((l >> 4) ^ ((l >> 1) & 3)) << 3);
    for (int kt = 0; kt < K; kt += 32) {
        gload_lds16(A + rA0 + kt + lk, &tA[w << 9]);
        gload_lds16(A + rA1 + kt + lk, &tA[2048 + (w << 9)]);
        gload_lds16(Bt + rB0 + kt + lk, &tB[w << 9]);
        gload_lds16(Bt + rB1 + kt + lk, &tB[2048 + (w << 9)]);
        __syncthreads();
        bf16x8 av[4], bv[4];
#pragma unroll
        for (int i = 0; i < 4; ++i) {
            av[i] = *(const bf16x8*)&tA[((wm + (i << 4) + frow) << 5) + koff];
            bv[i] = *(const bf16x8*)&tB[((wn + (i << 4) + frow) << 5) + koff];
        }
#pragma unroll
        for (int i = 0; i < 4; ++i)
#pragma unroll
            for (int j = 0; j < 4; ++j)
                acc[i][j] = __builtin_amdgcn_mfma_f32_16x16x32_bf16(av[i], bv[j], acc[i][j], 0, 0, 0);
        __syncthreads();
    }
    const int crow = bm + wm + ((l >> 4) << 2);
    const int ccol = n0 + wn + (l & 15);
#pragma unroll
    for (int i = 0; i < 4; ++i)
#pragma unroll
        for (int j = 0; j < 4; ++j)
#pragma unroll
            for (int jj = 0; jj < 4; ++jj)
                C[(size_t)(crow + (i << 4) + jj) * N2 + ccol + (j << 4)] = acc[i][j][jj];
}

// ---------- Y1 -> X2 (bf16): [tanh(xw) | xa | sigmoid(xg) | xv | xk] ----------
__global__ __launch_bounds__(256) void k_prep_x2(const float* __restrict__ Y1, u16* __restrict__ X2) {
    int idx = blockIdx.x * 256 + threadIdx.x;   // t*576 + c
    int t = idx / 576, c = idx - t * 576;
    const float* y1 = Y1 + (size_t)t * N1;
    float v;
    if (c < 96)       v = tanhf(y1[c]);
    else if (c < 192) v = y1[c];
    else if (c < 448) v = sigm(y1[c + 64]);
    else if (c < 512) v = y1[c - 256];
    else              v = y1[c];
    X2[idx] = f2bf(v);
}

// ---------- per-token recurrence prep (+ RD = R.D, per-step scalars rk, rb) ----------
__global__ __launch_bounds__(256) void k_prep_rec(
    const float* __restrict__ Y1, const float* __restrict__ Y2,
    const float* __restrict__ v_first, const float* __restrict__ k_first,
    const float* __restrict__ cosb, const float* __restrict__ sinb,
    const float* __restrict__ w0, const float* __restrict__ a0,
    const float* __restrict__ v0b, const float* __restrict__ k0b,
    const float* __restrict__ R_bias, const float* __restrict__ K_bias,
    const float* __restrict__ V_bias, const float* __restrict__ ln_r,
    const float* __restrict__ ln_k,
    float* __restrict__ RR, float* __restrict__ DEC, float* __restrict__ KR,
    float* __restrict__ VV, float* __restrict__ AA, float* __restrict__ BB,
    float* __restrict__ RD, float* __restrict__ RKB) {
    const int t = blockIdx.x, tid = threadIdx.x;
    const int ww = tid >> 6, lane = tid & 63;
    const float* y1 = Y1 + (size_t)t * N1;
    const float* y2 = Y2 + (size_t)t * N2;
    const float cs = cosb[t * 64 + lane];
    const float sn = sinb[t * 64 + lane];
    const float sign = lane < 32 ? -1.f : 1.f;
    const size_t tb = (size_t)t << 11;
    __shared__ float kkv[512], vkv[512];
    float rsave[8];
    // r: per-head rmsnorm + rope
#pragma unroll
    for (int i = 0; i < 8; ++i) {
        int h = ww * 8 + i, c = h * 64 + lane;
        float rr = y1[576 + c] + R_bias[c];
        float ssq = wsum(rr * rr);
        float rn = ln_r[lane] * rr * rsqrtf(ssq * (1.f / 64.f) + 1e-6f);
        float rot = sign * __shfl(rn, lane ^ 32, 64);
        rsave[i] = rn * cs + rot * sn;
        RR[tb + c] = rsave[i];
    }
    // k,v kv-heads: rmsnorm+rope+mix
#pragma unroll
    for (int i = 0; i < 2; ++i) {
        int j = ww * 2 + i, c = j * 64 + lane;
        float kr = y1[2624 + c] + K_bias[c];
        float ssq = wsum(kr * kr);
        float kn = ln_k[lane] * kr * rsqrtf(ssq * (1.f / 64.f) + 1e-6f);
        float rot = sign * __shfl(kn, lane ^ 32, 64);
        float krope = kn * cs + rot * sn;
        float ksig = sigm(y2[6656 + c] + k0b[c]);
        kkv[c] = krope + (k_first[(size_t)t * 512 + c] - krope) * ksig;
        float vr = y1[3136 + c] + V_bias[c];
        float vsig = sigm(y2[6144 + c] + v0b[c]);
        vkv[c] = vr + (v_first[(size_t)t * 512 + c] - vr) * vsig;
    }
    __syncthreads();
    // per-head final recurrence operands
#pragma unroll
    for (int i = 0; i < 8; ++i) {
        int h = ww * 8 + i, c = h * 64 + lane;
        int ckv = (h >> 2) * 64 + lane;
        float kb = kkv[ckv], vb = vkv[ckv];
        float a_ = sigm(y2[2048 + c] + a0[c]);
        float wr = y2[c] + w0[c];
        float z = -wr;
        float sp = fmaxf(z, 0.f) + log1pf(expf(-fabsf(z)));
        float w_log = -sp - 0.5f;
        float ssq = wsum(kb * kb);
        float kk = kb / fmaxf(sqrtf(ssq), 1e-12f);
        const float dec = expf(-expf(w_log));
        const float kr2 = kb * (1.f - w_log + a_);
        const float bb2 = kk * a_;
        const float rrv = rsave[i];
        DEC[tb + c] = dec;
        KR[tb + c] = kr2;
        VV[tb + c] = vb;
        AA[tb + c] = -kk;
        BB[tb + c] = bb2;
        RD[tb + c] = rrv * dec;
        const float rk = wsum(rrv * kr2);
        const float rb = wsum(rrv * bb2);
        if (lane == 0) {
            const int chain = (t >> 10) * 32 + h;
            RKB[(size_t)chain * 2048 + ((t & 1023) << 1)] = rk;
            RKB[(size_t)chain * 2048 + ((t & 1023) << 1) + 1] = rb;
        }
    }
}

// ---------- sequential recurrence: decoupled-o formulation ----------
// o = (R.D)·S_old + rk·V + rb·sa : both reductions act on OLD S and interleave
// (two independent DPP chains), and o falls off the cross-step serial chain
// (which is now just A·S -> rowsum -> update). rk/rb per-step scalars staged in
// a tiny LDS tail; RD staged in place of R.
__global__ __launch_bounds__(256, 1) void k_recv11(
    const float* __restrict__ DECp, const float* __restrict__ KRp,
    const float* __restrict__ VVp, const float* __restrict__ AAp,
    const float* __restrict__ BBp, const float* __restrict__ RDp,
    const float* __restrict__ RKBp,
    const float* __restrict__ S0, float* __restrict__ OO) {
    __shared__ __align__(16) float cbuf[2][6][32][64];   // [dbuf][arr][t][64] = 96 KB
    __shared__ float tailb[2][64];                       // [dbuf][2*32] rk,rb pairs
    const int tid = threadIdx.x;
    const int wl = tid >> 6;           // wave 0..3
    const int lane = tid & 63;
    const int vl = lane >> 4;          // DPP row 0..3
    const int kq = lane & 15;          // k-quad 0..15
    const int quarter = blockIdx.x & 3;
    const int ch = blockIdx.x >> 2;          // chain 0..63 (b*32+h)
    const int vcol = (quarter << 4) + (wl << 2) + vl;   // this row's v-column
    const size_t cb = ((size_t)(ch >> 5) * 1024 * 2048) + ((size_t)(ch & 31) << 6);

    // state: Lj = S[4kq+j][vcol]
    const float* s0 = S0 + ((size_t)ch << 12);
    float L0 = s0[((kq << 2) + 0) * 64 + vcol];
    float L1 = s0[((kq << 2) + 1) * 64 + vcol];
    float L2 = s0[((kq << 2) + 2) * 64 + vcol];
    float L3 = s0[((kq << 2) + 3) * 64 + vcol];

    const float* gsrc[6] = {AAp, DECp, KRp, BBp, RDp, VVp};
    const int trow = (wl << 2) + vl;   // 0..15; rows trow and trow+16 staged

#define STG(B, T0)                                                             \
    {                                                                          \
        const size_t g0 = cb + (size_t)((T0) + trow) * 2048 + (kq << 2);       \
        const size_t g1 = cb + (size_t)((T0) + 16 + trow) * 2048 + (kq << 2);  \
        float* lb = &cbuf[B][0][0][0] + (wl << 8);                             \
        _Pragma("unroll") for (int ar = 0; ar < 6; ++ar) {                     \
            gload_lds16(gsrc[ar] + g0, lb + ar * 2048);                        \
            gload_lds16(gsrc[ar] + g1, lb + ar * 2048 + 1024);                 \
        }                                                                      \
        if (wl == 0)                                                           \
            tailb[B][lane] = RKBp[(size_t)ch * 2048 + ((T0) << 1) + lane];     \
    }

#define LDC(P, TL, S)                                                          \
    A4 = *(const float4*)((P) + ((S) << 6) + (kq << 2));                       \
    D4 = *(const float4*)((P) + 2048 + ((S) << 6) + (kq << 2));                \
    K4 = *(const float4*)((P) + 4096 + ((S) << 6) + (kq << 2));                \
    B4 = *(const float4*)((P) + 6144 + ((S) << 6) + (kq << 2));                \
    R4 = *(const float4*)((P) + 8192 + ((S) << 6) + (kq << 2));                \
    Vs = (P)[10240 + ((S) << 6) + vcol];                                       \
    RK2 = *(const float2*)((TL) + ((S) << 1));

    STG(0, 0);
    __syncthreads();

    float4 A4, D4, K4, B4, R4;   // R4 holds RD (R.D)
    float Vs;
    float2 RK2;                  // (rk, rb)
    {
        const float* bp0 = &cbuf[0][0][0][0];
        LDC(bp0, &tailb[0][0], 0);
    }

    for (int c = 0; c < 32; ++c) {
        const int b = c & 1;
        if (c < 31) STG(b ^ 1, (c + 1) << 5);      // async prefetch next chunk
        const float* cp = &cbuf[b][0][0][0];
        const float* tl = &tailb[b][0];
#pragma unroll 4
        for (int s = 0; s < 32; ++s) {
            // prefetch step s+1 (s=31 -> dummy re-read of step 0, overwritten later)
            const int sn = (s + 1) & 31;
            const int so = sn << 6;
            const float4 nA = *(const float4*)(cp + so + (kq << 2));
            const float4 nD = *(const float4*)(cp + 2048 + so + (kq << 2));
            const float4 nK = *(const float4*)(cp + 4096 + so + (kq << 2));
            const float4 nB = *(const float4*)(cp + 6144 + so + (kq << 2));
            const float4 nR = *(const float4*)(cp + 8192 + so + (kq << 2));
            const float  nV = cp[10240 + so + vcol];
            const float2 nRK = *(const float2*)(tl + (sn << 1));
            // two independent reductions over OLD S (DPP chains interleave)
            float sp = fmaf(L1, A4.y, L0 * A4.x) + fmaf(L3, A4.w, L2 * A4.z);
            float od = fmaf(L1, R4.y, L0 * R4.x) + fmaf(L3, R4.w, L2 * R4.z);
            const float sa = rowsum16(sp);
            const float odr = rowsum16(od);
            // state update (the only cross-step chain)
            L0 = fmaf(B4.x, sa, fmaf(K4.x, Vs, L0 * D4.x));
            L1 = fmaf(B4.y, sa, fmaf(K4.y, Vs, L1 * D4.y));
            L2 = fmaf(B4.z, sa, fmaf(K4.z, Vs, L2 * D4.z));
            L3 = fmaf(B4.w, sa, fmaf(K4.w, Vs, L3 * D4.w));
            // o path (off-chain)
            const float o = odr + fmaf(RK2.x, Vs, RK2.y * sa);
            if (kq == 0) OO[cb + ((size_t)((c << 5) + s) << 11) + vcol] = o;
            A4 = nA; D4 = nD; K4 = nK; B4 = nB; R4 = nR; Vs = nV; RK2 = nRK;
        }
        __syncthreads();   // drains staging vmcnt; flips buffers
        if (c < 31) {
            const float* np = &cbuf[b ^ 1][0][0][0];
            LDC(np, &tailb[b ^ 1][0], 0);    // preload step 0 of next chunk
        }
    }
#undef LDC
#undef STG
}

// ---------- bonus + gate -> bf16 ----------
__global__ __launch_bounds__(256) void k_gate(
    const float* __restrict__ OOp, const float* __restrict__ RRp,
    const float* __restrict__ KRp, const float* __restrict__ VVp,
    const float* __restrict__ Y2, const float* __restrict__ r_k,
    u16* __restrict__ XG) {
    const int t = blockIdx.x, tid = threadIdx.x;
    const int ww = tid >> 6, lane = tid & 63;
    const size_t tb = (size_t)t << 11;
#pragma unroll
    for (int i = 0; i < 8; ++i) {
        int c = (ww * 8 + i) * 64 + lane;
        float pr = RRp[tb + c] * KRp[tb + c] * r_k[c];
        float dot = wsum(pr);
        float xx = OOp[tb + c] * 0.125f + dot * VVp[tb + c];
        float g = Y2[(size_t)t * N2 + 4096 + c];
        XG[tb + c] = f2bf(xx * g);
    }
}

// ---------- final residual + rmsnorm ----------
__global__ __launch_bounds__(256) void k_final(const float* __restrict__ x_in,
                                               const float* __restrict__ OUTR,
                                               const float* __restrict__ ln2,
                                               float* __restrict__ out) {
    const int t = blockIdx.x, tid = threadIdx.x;
    const float* xr = x_in + ((size_t)t << 11);
    const float* orow = OUTR + ((size_t)t << 11);
    float4 a0 = *(const float4*)(xr + tid * 8);
    float4 a1 = *(const float4*)(xr + tid * 8 + 4);
    float4 b0 = *(const float4*)(orow + tid * 8);
    float4 b1 = *(const float4*)(orow + tid * 8 + 4);
    float v[8] = {a0.x + b0.x, a0.y + b0.y, a0.z + b0.z, a0.w + b0.w,
                  a1.x + b1.x, a1.y + b1.y, a1.z + b1.z, a1.w + b1.w};
    float ss = 0.f;
#pragma unroll
    for (int i = 0; i < 8; ++i) ss = fmaf(v[i], v[i], ss);
    ss = wsum(ss);
    __shared__ float red[4];
    if ((tid & 63) == 0) red[tid >> 6] = ss;
    __syncthreads();
    float scale = rsqrtf((red[0] + red[1] + red[2] + red[3]) * (1.f / 2048.f) + 1e-6f);
    float* o = out + ((size_t)t << 11) + tid * 8;
#pragma unroll
    for (int i = 0; i < 8; ++i) o[i] = ln2[tid * 8 + i] * v[i] * scale;
}

extern "C" void kernel_launch(void* const* d_in, const int* in_sizes, int n_in,
                              void* d_out, int out_size, void* d_ws, size_t ws_size,
                              hipStream_t stream) {
    const float* x_in    = (const float*)d_in[0];
    const float* v_first = (const float*)d_in[1];
    const float* k_first = (const float*)d_in[2];
    const float* state   = (const float*)d_in[3];
    const float* cosb    = (const float*)d_in[4];
    const float* sinb    = (const float*)d_in[5];
    const float* wavgk1  = (const float*)d_in[6];
    const float* w0      = (const float*)d_in[7];
    const float* w2      = (const float*)d_in[8];
    const float* a0      = (const float*)d_in[9];
    const float* a2      = (const float*)d_in[10];
    const float* v0      = (const float*)d_in[11];
    const float* v2      = (const float*)d_in[12];
    const float* g2      = (const float*)d_in[13];
    const float* k0      = (const float*)d_in[14];
    const float* k2      = (const float*)d_in[15];
    const float* r_k     = (const float*)d_in[16];
    const float* RKV     = (const float*)d_in[17];
    const float* O       = (const float*)d_in[18];
    const float* R_bias  = (const float*)d_in[19];
    const float* K_bias  = (const float*)d_in[20];
    const float* V_bias  = (const float*)d_in[21];
    const float* ln_r    = (const float*)d_in[22];
    const float* ln_k    = (const float*)d_in[23];
    const float* ln1     = (const float*)d_in[24];
    const float* ln2     = (const float*)d_in[25];

    if (ws_size < WS_NEED) return;  // need 230.7 MB (fits 256 MiB)

    char* ws = (char*)d_ws;
    u16*   BT1  = (u16*)(ws + OFF_BT1);
    u16*   W2T  = (u16*)(ws + OFF_W2T);
    u16*   OT   = (u16*)(ws + OFF_OT);
    u16*   XB   = (u16*)(ws + OFF_XB);
    float* Y1   = (float*)(ws + OFF_Y1);
    u16*   X2   = (u16*)(ws + OFF_X2);
    float* Y2   = (float*)(ws + OFF_Y2);
    float* RR   = (float*)(ws + OFF_RR);
    float* DEC  = (float*)(ws + OFF_DEC);
    float* KR   = (float*)(ws + OFF_KR);
    float* VV   = (float*)(ws + OFF_VV);
    float* AA   = (float*)(ws + OFF_AA);
    float* BB   = (float*)(ws + OFF_BB);
    float* RKB  = (float*)(ws + OFF_RKB);
    float* RD   = (float*)(ws + OFF_RD);
    float* OO   = (float*)(ws + OFF_OO);
    u16*   XG   = (u16*)(ws + OFF_XG);
    float* OUTR = (float*)(ws + OFF_OUTR);

    // P0: BT1 + XB (region C)
    k_prep_bt1<<<1856, 256, 0, stream>>>(wavgk1, RKV, BT1);
    k_rms1<<<2048, 256, 0, stream>>>(x_in, ln1, XB);
    // P1: GEMM1 -> Y1  (region A)
    k_gemm<<<dim3(16, 29), 256, 0, stream>>>(XB, BT1, Y1, 2048, N1, 2048);
    // P2: W2T + X2 overwrite BT1/XB (dead); GEMM2 (block-diagonal) -> Y2 (region B)
    k_prep_w2t<<<16128, 256, 0, stream>>>(w2, a2, g2, v2, k2, W2T);
    k_prep_x2<<<4608, 256, 0, stream>>>(Y1, X2);
    k_gemm2<<<dim3(16, 56), 256, 0, stream>>>(X2, W2T, Y2);
    // P3: recurrence operands (region D); Y1 dead after this
    k_prep_rec<<<2048, 256, 0, stream>>>(Y1, Y2, v_first, k_first, cosb, sinb,
                                         w0, a0, v0, k0, R_bias, K_bias, V_bias,
                                         ln_r, ln_k, RR, DEC, KR, VV, AA, BB, RD, RKB);
    // P4: OT overwrites W2T/X2 (dead); recurrence -> OO (in old Y1 space)
    k_prep_ot<<<1024, 256, 0, stream>>>(O, OT);
    k_recv11<<<256, 256, 0, stream>>>(DEC, KR, VV, AA, BB, RD, RKB, state, OO);
    // P5: gate -> XG (in old Y1 space); Y2 dead after this
    k_gate<<<2048, 256, 0, stream>>>(OO, RR, KR, VV, Y2, r_k, XG);
    // P6: GEMM3 -> OUTR (in old Y2 space); final norm
    k_gemm<<<dim3(16, 16), 256, 0, stream>>>(XG, OT, OUTR, 2048, 2048, 2048);
    k_final<<<2048, 256, 0, stream>>>(x_in, OUTR, ln2, (float*)d_out);
}

// Round 20
// 384.813 us; speedup vs baseline: 1.0911x; 1.0911x over previous
//
#include <hip/hip_runtime.h>

typedef unsigned short u16;
typedef unsigned int u32;

using f32x4 = __attribute__((ext_vector_type(4))) float;
using bf16x8 = __attribute__((ext_vector_type(8))) __bf16;

// ---------- constants ----------
#define HN 2048
#define KVD 512
#define TOKENS 2048          // B*T
#define N1 3712              // GEMM1 N (3648 padded to 29*128)
#define K2W 576              // GEMM2 K
#define N2 7168              // GEMM2 N: w(2048) a(2048) g(2048) v(512) k(512)

// ---------- workspace layout (bytes) — lifetime-aliased, peak 213.4 MB ----------
#define OFF_Y1   0ull
#define OFF_OO   0ull
#define OFF_XG   16777216ull
#define OFF_Y2   30408704ull
#define OFF_OUTR 30408704ull
#define OFF_BT1  89128960ull
#define OFF_XB   104333312ull
#define OFF_W2T  89128960ull
#define OFF_X2   97386496ull
#define OFF_OT   89128960ull
#define OFF_RR   112721920ull
#define OFF_DEC  129499136ull
#define OFF_KR   146276352ull
#define OFF_VV   163053568ull
#define OFF_AA   179830784ull
#define OFF_BB   196608000ull
#define WS_NEED  213385216ull

// ---------- helpers ----------
__device__ __forceinline__ u16 f2bf(float f) {
    u32 u = __float_as_uint(f);
    u32 r = u + 0x7fffu + ((u >> 16) & 1u);
    return (u16)(r >> 16);
}
__device__ __forceinline__ float sigm(float x) { return 1.f / (1.f + expf(-x)); }
__device__ __forceinline__ float wsum(float v) {
#pragma unroll
    for (int m = 32; m > 0; m >>= 1) v += __shfl_xor(v, m, 64);
    return v;
}
// sum across each 16-lane DPP row via row_ror 1,2,4,8; result in all lanes of the row
__device__ __forceinline__ float rowsum16(float v) {
    float t;
    t = __uint_as_float(__builtin_amdgcn_update_dpp(0, __float_as_uint(v), 0x121, 0xf, 0xf, true));
    v += t;
    t = __uint_as_float(__builtin_amdgcn_update_dpp(0, __float_as_uint(v), 0x122, 0xf, 0xf, true));
    v += t;
    t = __uint_as_float(__builtin_amdgcn_update_dpp(0, __float_as_uint(v), 0x124, 0xf, 0xf, true));
    v += t;
    t = __uint_as_float(__builtin_amdgcn_update_dpp(0, __float_as_uint(v), 0x128, 0xf, 0xf, true));
    v += t;
    return v;
}

typedef __attribute__((address_space(1))) const void glob_t;
typedef __attribute__((address_space(3))) void lds_t;
__device__ __forceinline__ void gload_lds16(const void* g, void* l) {
    __builtin_amdgcn_global_load_lds((glob_t*)g, (lds_t*)l, 16, 0, 0);
}

// inline-asm LDS readers with literal offset (burst-issued, order preserved)
template<int OFF>
__device__ __forceinline__ float4 ds_read128(u32 a) {
    float4 r;
    asm volatile("ds_read_b128 %0, %1 offset:%2" : "=v"(r) : "v"(a), "i"(OFF));
    return r;
}
template<int OFF>
__device__ __forceinline__ float ds_read32(u32 a) {
    float r;
    asm volatile("ds_read_b32 %0, %1 offset:%2" : "=v"(r) : "v"(a), "i"(OFF));
    return r;
}

// ---------- weight prep: tiled transposes (coalesced read AND write) ----------
__global__ __launch_bounds__(256) void k_prep_bt1(const float* __restrict__ wavgk1,
                                                  const float* __restrict__ RKV,
                                                  u16* __restrict__ BT1) {
    __shared__ float tile[64][65];
    const int bn = blockIdx.x >> 5;        // 0..57
    const int bk = blockIdx.x & 31;        // 0..31
    const int n0 = bn << 6, k0 = bk << 6;
    const int c = threadIdx.x & 63, q = threadIdx.x >> 6;
#pragma unroll
    for (int i = 0; i < 16; ++i) {
        const int r = (q << 4) + i;
        float v = 0.f;
        if (bn < 9)       v = wavgk1[(size_t)(k0 + r) * 576 + n0 + c];
        else if (bn < 57) v = RKV[(size_t)(k0 + r) * 3072 + (n0 + c - 576)];
        tile[r][c] = v;
    }
    __syncthreads();
#pragma unroll
    for (int i = 0; i < 16; ++i) {
        const int rw = (q << 4) + i;
        BT1[(size_t)(n0 + rw) * 2048 + k0 + c] = f2bf(tile[c][rw]);
    }
}

__global__ __launch_bounds__(256) void k_prep_w2t(const float* __restrict__ w2, const float* __restrict__ a2,
                                                  const float* __restrict__ g2, const float* __restrict__ v2,
                                                  const float* __restrict__ k2, u16* __restrict__ W2T) {
    int idx = blockIdx.x * 256 + threadIdx.x;   // n*576 + c, n<7168
    int n = idx / 576, c = idx - n * 576;
    float v = 0.f;
    if (n < 2048)      { if (c < 96)              v = w2[(size_t)c * 2048 + n]; }
    else if (n < 4096) { if (c >= 96 && c < 192)  v = a2[(size_t)(c - 96) * 2048 + (n - 2048)]; }
    else if (n < 6144) { if (c >= 192 && c < 448) v = g2[(size_t)(c - 192) * 2048 + (n - 4096)]; }
    else if (n < 6656) { if (c >= 448 && c < 512) v = v2[(size_t)(c - 448) * 512 + (n - 6144)]; }
    else               { if (c >= 512)            v = k2[(size_t)(c - 512) * 512 + (n - 6656)]; }
    W2T[idx] = f2bf(v);
}

// OT[n][k] = O[k][n], 2048x2048, 64x64 tiles
__global__ __launch_bounds__(256) void k_prep_ot(const float* __restrict__ O, u16* __restrict__ OT) {
    __shared__ float tile[64][65];
    const int bn = blockIdx.x >> 5, bk = blockIdx.x & 31;
    const int n0 = bn << 6, k0 = bk << 6;
    const int c = threadIdx.x & 63, q = threadIdx.x >> 6;
#pragma unroll
    for (int i = 0; i < 16; ++i) {
        const int r = (q << 4) + i;
        tile[r][c] = O[(size_t)(k0 + r) * 2048 + n0 + c];
    }
    __syncthreads();
#pragma unroll
    for (int i = 0; i < 16; ++i) {
        const int rw = (q << 4) + i;
        OT[(size_t)(n0 + rw) * 2048 + k0 + c] = f2bf(tile[c][rw]);
    }
}

// ---------- rmsnorm(x_in, ln1) -> bf16 ----------
__global__ __launch_bounds__(256) void k_rms1(const float* __restrict__ X,
                                              const float* __restrict__ ln1,
                                              u16* __restrict__ XB) {
    const int t = blockIdx.x, tid = threadIdx.x;
    const float* row = X + ((size_t)t << 11);
    float4 v0 = *(const float4*)(row + tid * 8);
    float4 v1 = *(const float4*)(row + tid * 8 + 4);
    float ss = v0.x*v0.x + v0.y*v0.y + v0.z*v0.z + v0.w*v0.w
             + v1.x*v1.x + v1.y*v1.y + v1.z*v1.z + v1.w*v1.w;
    ss = wsum(ss);
    __shared__ float red[4];
    if ((tid & 63) == 0) red[tid >> 6] = ss;
    __syncthreads();
    float scale = rsqrtf((red[0] + red[1] + red[2] + red[3]) * (1.f / 2048.f) + 1e-6f);
    float4 w0_ = *(const float4*)(ln1 + tid * 8);
    float4 w1_ = *(const float4*)(ln1 + tid * 8 + 4);
    u16* o = XB + ((size_t)t << 11) + tid * 8;
    o[0] = f2bf(v0.x * scale * w0_.x); o[1] = f2bf(v0.y * scale * w0_.y);
    o[2] = f2bf(v0.z * scale * w0_.z); o[3] = f2bf(v0.w * scale * w0_.w);
    o[4] = f2bf(v1.x * scale * w1_.x); o[5] = f2bf(v1.y * scale * w1_.y);
    o[6] = f2bf(v1.z * scale * w1_.z); o[7] = f2bf(v1.w * scale * w1_.w);
}

// ---------- generic bf16 MFMA GEMM with LDS chunk swizzle ----------
__global__ __launch_bounds__(256) void k_gemm(const u16* __restrict__ A,
                                              const u16* __restrict__ Bt,
                                              float* __restrict__ C,
                                              int M, int N, int K) {
    __shared__ __align__(16) u16 tA[4096];  // [128 rows][32 k]
    __shared__ __align__(16) u16 tB[4096];
    const int tid = threadIdx.x;
    const int w = tid >> 6, l = tid & 63;
    const int bm = blockIdx.x << 7, bn = blockIdx.y << 7;
    const int wm = (w >> 1) << 6, wn = (w & 1) << 6;
    const int lrow = l >> 2;        // 0..15 (staged row within 16-row group)
    const int lk = (((l & 3) ^ ((l >> 3) & 3)) << 3);   // pre-swizzled global chunk
    f32x4 acc[4][4] = {};
    const size_t rA0 = (size_t)(bm + (w << 4) + lrow) * K;
    const size_t rA1 = (size_t)(bm + ((w + 4) << 4) + lrow) * K;
    const size_t rB0 = (size_t)(bn + (w << 4) + lrow) * K;
    const size_t rB1 = (size_t)(bn + ((w + 4) << 4) + lrow) * K;
    const int frow = l & 15;
    const int koff = (((l >> 4) ^ ((l >> 1) & 3)) << 3);  // swizzled read chunk
    for (int kt = 0; kt < K; kt += 32) {
        gload_lds16(A + rA0 + kt + lk, &tA[w << 9]);
        gload_lds16(A + rA1 + kt + lk, &tA[2048 + (w << 9)]);
        gload_lds16(Bt + rB0 + kt + lk, &tB[w << 9]);
        gload_lds16(Bt + rB1 + kt + lk, &tB[2048 + (w << 9)]);
        __syncthreads();
        bf16x8 av[4], bv[4];
#pragma unroll
        for (int i = 0; i < 4; ++i) {
            av[i] = *(const bf16x8*)&tA[((wm + (i << 4) + frow) << 5) + koff];
            bv[i] = *(const bf16x8*)&tB[((wn + (i << 4) + frow) << 5) + koff];
        }
#pragma unroll
        for (int i = 0; i < 4; ++i)
#pragma unroll
            for (int j = 0; j < 4; ++j)
                acc[i][j] = __builtin_amdgcn_mfma_f32_16x16x32_bf16(av[i], bv[j], acc[i][j], 0, 0, 0);
        __syncthreads();
    }
    const int crow = bm + wm + ((l >> 4) << 2);
    const int ccol = bn + wn + (l & 15);
#pragma unroll
    for (int i = 0; i < 4; ++i)
#pragma unroll
        for (int j = 0; j < 4; ++j)
#pragma unroll
            for (int jj = 0; jj < 4; ++jj)
                C[(size_t)(crow + (i << 4) + jj) * N + ccol + (j << 4)] = acc[i][j][jj];
}

// ---------- GEMM2 specialization: block-diagonal W2T, per-segment true K ----------
__global__ __launch_bounds__(256) void k_gemm2(const u16* __restrict__ A,
                                               const u16* __restrict__ Bt,
                                               float* __restrict__ C) {
    __shared__ __align__(16) u16 tA[4096];
    __shared__ __align__(16) u16 tB[4096];
    const int tid = threadIdx.x;
    const int w = tid >> 6, l = tid & 63;
    const int by = blockIdx.y;
    int c0, K;
    if (by < 16)      { c0 = 0;   K = 96; }
    else if (by < 32) { c0 = 96;  K = 96; }
    else if (by < 48) { c0 = 192; K = 256; }
    else if (by < 52) { c0 = 448; K = 64; }
    else              { c0 = 512; K = 64; }
    const int n0 = by << 7;
    const int bm = blockIdx.x << 7;
    const int wm = (w >> 1) << 6, wn = (w & 1) << 6;
    const int lrow = l >> 2;
    const int lk = (((l & 3) ^ ((l >> 3) & 3)) << 3);
    f32x4 acc[4][4] = {};
    const size_t rA0 = (size_t)(bm + (w << 4) + lrow) * 576 + c0;
    const size_t rA1 = (size_t)(bm + ((w + 4) << 4) + lrow) * 576 + c0;
    const size_t rB0 = (size_t)(n0 + (w << 4) + lrow) * 576 + c0;
    const size_t rB1 = (size_t)(n0 + ((w + 4) << 4) + lrow) * 576 + c0;
    const int frow = l & 15;
    const int koff = (((l >> 4) ^ ((l >> 1) & 3)) << 3);
    for (int kt = 0; kt < K; kt += 32) {
        gload_lds16(A + rA0 + kt + lk, &tA[w << 9]);
        gload_lds16(A + rA1 + kt + lk, &tA[2048 + (w << 9)]);
        gload_lds16(Bt + rB0 + kt + lk, &tB[w << 9]);
        gload_lds16(Bt + rB1 + kt + lk, &tB[2048 + (w << 9)]);
        __syncthreads();
        bf16x8 av[4], bv[4];
#pragma unroll
        for (int i = 0; i < 4; ++i) {
            av[i] = *(const bf16x8*)&tA[((wm + (i << 4) + frow) << 5) + koff];
            bv[i] = *(const bf16x8*)&tB[((wn + (i << 4) + frow) << 5) + koff];
        }
#pragma unroll
        for (int i = 0; i < 4; ++i)
#pragma unroll
            for (int j = 0; j < 4; ++j)
                acc[i][j] = __builtin_amdgcn_mfma_f32_16x16x32_bf16(av[i], bv[j], acc[i][j], 0, 0, 0);
        __syncthreads();
    }
    const int crow = bm + wm + ((l >> 4) << 2);
    const int ccol = n0 + wn + (l & 15);
#pragma unroll
    for (int i = 0; i < 4; ++i)
#pragma unroll
        for (int j = 0; j < 4; ++j)
#pragma unroll
            for (int jj = 0; jj < 4; ++jj)
                C[(size_t)(crow + (i << 4) + jj) * N2 + ccol + (j << 4)] = acc[i][j][jj];
}

// ---------- Y1 -> X2 (bf16): [tanh(xw) | xa | sigmoid(xg) | xv | xk] ----------
__global__ __launch_bounds__(256) void k_prep_x2(const float* __restrict__ Y1, u16* __restrict__ X2) {
    int idx = blockIdx.x * 256 + threadIdx.x;   // t*576 + c
    int t = idx / 576, c = idx - t * 576;
    const float* y1 = Y1 + (size_t)t * N1;
    float v;
    if (c < 96)       v = tanhf(y1[c]);
    else if (c < 192) v = y1[c];
    else if (c < 448) v = sigm(y1[c + 64]);
    else if (c < 512) v = y1[c - 256];
    else              v = y1[c];
    X2[idx] = f2bf(v);
}

// ---------- per-token recurrence prep ----------
__global__ __launch_bounds__(256) void k_prep_rec(
    const float* __restrict__ Y1, const float* __restrict__ Y2,
    const float* __restrict__ v_first, const float* __restrict__ k_first,
    const float* __restrict__ cosb, const float* __restrict__ sinb,
    const float* __restrict__ w0, const float* __restrict__ a0,
    const float* __restrict__ v0b, const float* __restrict__ k0b,
    const float* __restrict__ R_bias, const float* __restrict__ K_bias,
    const float* __restrict__ V_bias, const float* __restrict__ ln_r,
    const float* __restrict__ ln_k,
    float* __restrict__ RR, float* __restrict__ DEC, float* __restrict__ KR,
    float* __restrict__ VV, float* __restrict__ AA, float* __restrict__ BB) {
    const int t = blockIdx.x, tid = threadIdx.x;
    const int ww = tid >> 6, lane = tid & 63;
    const float* y1 = Y1 + (size_t)t * N1;
    const float* y2 = Y2 + (size_t)t * N2;
    const float cs = cosb[t * 64 + lane];
    const float sn = sinb[t * 64 + lane];
    const float sign = lane < 32 ? -1.f : 1.f;
    const size_t tb = (size_t)t << 11;
    __shared__ float kkv[512], vkv[512];
    // r: per-head rmsnorm + rope
#pragma unroll
    for (int i = 0; i < 8; ++i) {
        int h = ww * 8 + i, c = h * 64 + lane;
        float rr = y1[576 + c] + R_bias[c];
        float ssq = wsum(rr * rr);
        float rn = ln_r[lane] * rr * rsqrtf(ssq * (1.f / 64.f) + 1e-6f);
        float rot = sign * __shfl(rn, lane ^ 32, 64);
        RR[tb + c] = rn * cs + rot * sn;
    }
    // k,v kv-heads: rmsnorm+rope+mix
#pragma unroll
    for (int i = 0; i < 2; ++i) {
        int j = ww * 2 + i, c = j * 64 + lane;
        float kr = y1[2624 + c] + K_bias[c];
        float ssq = wsum(kr * kr);
        float kn = ln_k[lane] * kr * rsqrtf(ssq * (1.f / 64.f) + 1e-6f);
        float rot = sign * __shfl(kn, lane ^ 32, 64);
        float krope = kn * cs + rot * sn;
        float ksig = sigm(y2[6656 + c] + k0b[c]);
        kkv[c] = krope + (k_first[(size_t)t * 512 + c] - krope) * ksig;
        float vr = y1[3136 + c] + V_bias[c];
        float vsig = sigm(y2[6144 + c] + v0b[c]);
        vkv[c] = vr + (v_first[(size_t)t * 512 + c] - vr) * vsig;
    }
    __syncthreads();
    // per-head final recurrence operands
#pragma unroll
    for (int i = 0; i < 8; ++i) {
        int h = ww * 8 + i, c = h * 64 + lane;
        int ckv = (h >> 2) * 64 + lane;
        float kb = kkv[ckv], vb = vkv[ckv];
        float a_ = sigm(y2[2048 + c] + a0[c]);
        float wr = y2[c] + w0[c];
        float z = -wr;
        float sp = fmaxf(z, 0.f) + log1pf(expf(-fabsf(z)));
        float w_log = -sp - 0.5f;
        float ssq = wsum(kb * kb);
        float kk = kb / fmaxf(sqrtf(ssq), 1e-12f);
        DEC[tb + c] = expf(-expf(w_log));
        KR[tb + c] = kb * (1.f - w_log + a_);
        VV[tb + c] = vb;
        AA[tb + c] = -kk;
        BB[tb + c] = kk * a_;
    }
}

// ---------- sequential recurrence: 4 blocks/chain, asm burst-load groups ----------
// The ~440 cyc/step floor was per-step exposed ds_read latency (compiler sinks
// loads to uses; C++ prefetch attempts collapsed — r16/r18). Fix: groups of 8
// steps; 48 ds_reads issued as a VOLATILE ASM BURST (order preserved, pipeline
// in DS queue, single latency tail), then s_waitcnt lgkmcnt(0)+sched_barrier(0)
// (guide rule 18), then 8 steps of pure-register compute.
// cbuf[b][ar][s][x] byte offset = b*49152 + ar*8192 + s*256 + x*4.
__global__ __launch_bounds__(256, 1) void k_recv12(
    const float* __restrict__ RRp, const float* __restrict__ DECp,
    const float* __restrict__ KRp, const float* __restrict__ VVp,
    const float* __restrict__ AAp, const float* __restrict__ BBp,
    const float* __restrict__ S0, float* __restrict__ OO) {
    __shared__ __align__(16) float cbuf[2][6][32][64];   // [dbuf][arr][t][64] = 96 KB
    const int tid = threadIdx.x;
    const int wl = tid >> 6;           // wave 0..3
    const int lane = tid & 63;
    const int vl = lane >> 4;          // DPP row 0..3
    const int kq = lane & 15;          // k-quad 0..15
    const int quarter = blockIdx.x & 3;
    const int ch = blockIdx.x >> 2;          // chain 0..63 (b*32+h)
    const int vcol = (quarter << 4) + (wl << 2) + vl;   // this row's v-column
    const size_t cb = ((size_t)(ch >> 5) * 1024 * 2048) + ((size_t)(ch & 31) << 6);

    // state: Lj = S[4kq+j][vcol]
    const float* s0 = S0 + ((size_t)ch << 12);
    float L0 = s0[((kq << 2) + 0) * 64 + vcol];
    float L1 = s0[((kq << 2) + 1) * 64 + vcol];
    float L2 = s0[((kq << 2) + 2) * 64 + vcol];
    float L3 = s0[((kq << 2) + 3) * 64 + vcol];

    const float* gsrc[6] = {AAp, DECp, KRp, BBp, RRp, VVp};
    const int trow = (wl << 2) + vl;   // 0..15; rows trow and trow+16 staged

#define STG(B, T0)                                                             \
    {                                                                          \
        const size_t g0 = cb + (size_t)((T0) + trow) * 2048 + (kq << 2);       \
        const size_t g1 = cb + (size_t)((T0) + 16 + trow) * 2048 + (kq << 2);  \
        float* lb = &cbuf[B][0][0][0] + (wl << 8);                             \
        _Pragma("unroll") for (int ar = 0; ar < 6; ++ar) {                     \
            gload_lds16(gsrc[ar] + g0, lb + ar * 2048);                        \
            gload_lds16(gsrc[ar] + g1, lb + ar * 2048 + 1024);                 \
        }                                                                      \
    }

    // LDS byte address of cbuf base (generic->LDS offset: aperture is 4GB-aligned)
    const u32 base0 = (u32)(size_t)(void*)&cbuf[0][0][0][0];
    const u32 aA0 = base0 + (kq << 4);           // A-row chunk for this lane
    const u32 aV0 = base0 + 40960 + (vcol << 2); // V broadcast slot

#define LDSTEP(J)                                                              \
    cA[J] = ds_read128<(J) * 256>(aA);                                         \
    cD[J] = ds_read128<8192 + (J) * 256>(aA);                                  \
    cK[J] = ds_read128<16384 + (J) * 256>(aA);                                 \
    cB[J] = ds_read128<24576 + (J) * 256>(aA);                                 \
    cR[J] = ds_read128<32768 + (J) * 256>(aA);                                 \
    cV[J] = ds_read32<(J) * 256>(aV);

    STG(0, 0);
    __syncthreads();

    for (int c = 0; c < 32; ++c) {
        const int b = c & 1;
        if (c < 31) STG(b ^ 1, (c + 1) << 5);      // async prefetch next chunk
        u32 aA = aA0 + b * 49152;
        u32 aV = aV0 + b * 49152;
        int t = c << 5;
        for (int g = 0; g < 4; ++g) {              // 4 groups of 8 steps
            float4 cA[8], cD[8], cK[8], cB[8], cR[8];
            float cV[8];
            LDSTEP(0) LDSTEP(1) LDSTEP(2) LDSTEP(3)
            LDSTEP(4) LDSTEP(5) LDSTEP(6) LDSTEP(7)
            asm volatile("s_waitcnt lgkmcnt(0)" ::: "memory");
            __builtin_amdgcn_sched_barrier(0);
#pragma unroll
            for (int j = 0; j < 8; ++j) {
                const float4 A4 = cA[j], D4 = cD[j], K4 = cK[j], B4 = cB[j], R4 = cR[j];
                const float Vsj = cV[j];
                float sp = fmaf(L1, A4.y, L0 * A4.x) + fmaf(L3, A4.w, L2 * A4.z);
                const float sa = rowsum16(sp);
                L0 = fmaf(B4.x, sa, fmaf(K4.x, Vsj, L0 * D4.x));
                L1 = fmaf(B4.y, sa, fmaf(K4.y, Vsj, L1 * D4.y));
                L2 = fmaf(B4.z, sa, fmaf(K4.z, Vsj, L2 * D4.z));
                L3 = fmaf(B4.w, sa, fmaf(K4.w, Vsj, L3 * D4.w));
                float op = fmaf(L1, R4.y, L0 * R4.x) + fmaf(L3, R4.w, L2 * R4.z);
                const float o = rowsum16(op);
                if (kq == 0) OO[cb + ((size_t)(t + j) << 11) + vcol] = o;
            }
            t += 8;
            aA += 2048;
            aV += 2048;
        }
        __syncthreads();   // drains staging vmcnt (1/32 steps); flips buffers
    }
#undef LDSTEP
#undef STG
}

// ---------- bonus + gate -> bf16 ----------
__global__ __launch_bounds__(256) void k_gate(
    const float* __restrict__ OOp, const float* __restrict__ RRp,
    const float* __restrict__ KRp, const float* __restrict__ VVp,
    const float* __restrict__ Y2, const float* __restrict__ r_k,
    u16* __restrict__ XG) {
    const int t = blockIdx.x, tid = threadIdx.x;
    const int ww = tid >> 6, lane = tid & 63;
    const size_t tb = (size_t)t << 11;
#pragma unroll
    for (int i = 0; i < 8; ++i) {
        int c = (ww * 8 + i) * 64 + lane;
        float pr = RRp[tb + c] * KRp[tb + c] * r_k[c];
        float dot = wsum(pr);
        float xx = OOp[tb + c] * 0.125f + dot * VVp[tb + c];
        float g = Y2[(size_t)t * N2 + 4096 + c];
        XG[tb + c] = f2bf(xx * g);
    }
}

// ---------- final residual + rmsnorm ----------
__global__ __launch_bounds__(256) void k_final(const float* __restrict__ x_in,
                                               const float* __restrict__ OUTR,
                                               const float* __restrict__ ln2,
                                               float* __restrict__ out) {
    const int t = blockIdx.x, tid = threadIdx.x;
    const float* xr = x_in + ((size_t)t << 11);
    const float* orow = OUTR + ((size_t)t << 11);
    float4 a0 = *(const float4*)(xr + tid * 8);
    float4 a1 = *(const float4*)(xr + tid * 8 + 4);
    float4 b0 = *(const float4*)(orow + tid * 8);
    float4 b1 = *(const float4*)(orow + tid * 8 + 4);
    float v[8] = {a0.x + b0.x, a0.y + b0.y, a0.z + b0.z, a0.w + b0.w,
                  a1.x + b1.x, a1.y + b1.y, a1.z + b1.z, a1.w + b1.w};
    float ss = 0.f;
#pragma unroll
    for (int i = 0; i < 8; ++i) ss = fmaf(v[i], v[i], ss);
    ss = wsum(ss);
    __shared__ float red[4];
    if ((tid & 63) == 0) red[tid >> 6] = ss;
    __syncthreads();
    float scale = rsqrtf((red[0] + red[1] + red[2] + red[3]) * (1.f / 2048.f) + 1e-6f);
    float* o = out + ((size_t)t << 11) + tid * 8;
#pragma unroll
    for (int i = 0; i < 8; ++i) o[i] = ln2[tid * 8 + i] * v[i] * scale;
}

extern "C" void kernel_launch(void* const* d_in, const int* in_sizes, int n_in,
                              void* d_out, int out_size, void* d_ws, size_t ws_size,
                              hipStream_t stream) {
    const float* x_in    = (const float*)d_in[0];
    const float* v_first = (const float*)d_in[1];
    const float* k_first = (const float*)d_in[2];
    const float* state   = (const float*)d_in[3];
    const float* cosb    = (const float*)d_in[4];
    const float* sinb    = (const float*)d_in[5];
    const float* wavgk1  = (const float*)d_in[6];
    const float* w0      = (const float*)d_in[7];
    const float* w2      = (const float*)d_in[8];
    const float* a0      = (const float*)d_in[9];
    const float* a2      = (const float*)d_in[10];
    const float* v0      = (const float*)d_in[11];
    const float* v2      = (const float*)d_in[12];
    const float* g2      = (const float*)d_in[13];
    const float* k0      = (const float*)d_in[14];
    const float* k2      = (const float*)d_in[15];
    const float* r_k     = (const float*)d_in[16];
    const float* RKV     = (const float*)d_in[17];
    const float* O       = (const float*)d_in[18];
    const float* R_bias  = (const float*)d_in[19];
    const float* K_bias  = (const float*)d_in[20];
    const float* V_bias  = (const float*)d_in[21];
    const float* ln_r    = (const float*)d_in[22];
    const float* ln_k    = (const float*)d_in[23];
    const float* ln1     = (const float*)d_in[24];
    const float* ln2     = (const float*)d_in[25];

    if (ws_size < WS_NEED) return;  // need 213.4 MB (fits 256 MiB)

    char* ws = (char*)d_ws;
    u16*   BT1  = (u16*)(ws + OFF_BT1);
    u16*   W2T  = (u16*)(ws + OFF_W2T);
    u16*   OT   = (u16*)(ws + OFF_OT);
    u16*   XB   = (u16*)(ws + OFF_XB);
    float* Y1   = (float*)(ws + OFF_Y1);
    u16*   X2   = (u16*)(ws + OFF_X2);
    float* Y2   = (float*)(ws + OFF_Y2);
    float* RR   = (float*)(ws + OFF_RR);
    float* DEC  = (float*)(ws + OFF_DEC);
    float* KR   = (float*)(ws + OFF_KR);
    float* VV   = (float*)(ws + OFF_VV);
    float* AA   = (float*)(ws + OFF_AA);
    float* BB   = (float*)(ws + OFF_BB);
    float* OO   = (float*)(ws + OFF_OO);
    u16*   XG   = (u16*)(ws + OFF_XG);
    float* OUTR = (float*)(ws + OFF_OUTR);

    // P0: BT1 + XB (region C)
    k_prep_bt1<<<1856, 256, 0, stream>>>(wavgk1, RKV, BT1);
    k_rms1<<<2048, 256, 0, stream>>>(x_in, ln1, XB);
    // P1: GEMM1 -> Y1  (region A)
    k_gemm<<<dim3(16, 29), 256, 0, stream>>>(XB, BT1, Y1, 2048, N1, 2048);
    // P2: W2T + X2 overwrite BT1/XB (dead); GEMM2 (block-diagonal) -> Y2 (region B)
    k_prep_w2t<<<16128, 256, 0, stream>>>(w2, a2, g2, v2, k2, W2T);
    k_prep_x2<<<4608, 256, 0, stream>>>(Y1, X2);
    k_gemm2<<<dim3(16, 56), 256, 0, stream>>>(X2, W2T, Y2);
    // P3: recurrence operands (region D); Y1 dead after this
    k_prep_rec<<<2048, 256, 0, stream>>>(Y1, Y2, v_first, k_first, cosb, sinb,
                                         w0, a0, v0, k0, R_bias, K_bias, V_bias,
                                         ln_r, ln_k, RR, DEC, KR, VV, AA, BB);
    // P4: OT overwrites W2T/X2 (dead); recurrence -> OO (in old Y1 space)
    k_prep_ot<<<1024, 256, 0, stream>>>(O, OT);
    k_recv12<<<256, 256, 0, stream>>>(RR, DEC, KR, VV, AA, BB, state, OO);
    // P5: gate -> XG (in old Y1 space); Y2 dead after this
    k_gate<<<2048, 256, 0, stream>>>(OO, RR, KR, VV, Y2, r_k, XG);
    // P6: GEMM3 -> OUTR (in old Y2 space); final norm
    k_gemm<<<dim3(16, 16), 256, 0, stream>>>(XG, OT, OUTR, 2048, 2048, 2048);
    k_final<<<2048, 256, 0, stream>>>(x_in, OUTR, ln2, (float*)d_out);
}